// Round 4
// baseline (367.552 us; speedup 1.0000x reference)
//
#include <hip/hip_runtime.h>
#include <hip/hip_bf16.h>
#include <math.h>

#define TOKENS 8192
#define IN_F   1024
#define HID_F  4096
#define OUT_F  1024
#define NEXP   8
#define TSLOTS 72   // max total M-tiles: TOKENS/128 + NEXP partials

typedef __attribute__((ext_vector_type(8))) short bf16x8;
typedef __attribute__((ext_vector_type(4))) float f32x4;
typedef __attribute__((ext_vector_type(8))) unsigned short u16x8;

__device__ __forceinline__ unsigned short f2bf(float f) {
    unsigned int u = __float_as_uint(f);
    u += 0x7fffu + ((u >> 16) & 1u);   // round-to-nearest-even
    return (unsigned short)(u >> 16);
}

__device__ __forceinline__ void gload_lds16(const unsigned short* g, unsigned char* lds) {
    __builtin_amdgcn_global_load_lds(
        (const __attribute__((address_space(1))) void*)g,
        (__attribute__((address_space(3))) void*)lds, 16, 0, 0);
}

// ---------------- sort + tile-table build -----------------------------------
__global__ void sort_kernel(const int* __restrict__ idx, int* __restrict__ perm,
                            int* __restrict__ off, int* __restrict__ table) {
    __shared__ int cnt[NEXP];
    __shared__ int base[NEXP];
    const int tid = threadIdx.x, lane = tid & 63;
    if (tid < NEXP) cnt[tid] = 0;
    __syncthreads();
    for (int i = tid; i < TOKENS; i += 1024) {
        int e = idx[i];
#pragma unroll
        for (int ex = 0; ex < NEXP; ++ex) {
            unsigned long long m = __ballot(e == ex);
            if (lane == 0 && m) atomicAdd(&cnt[ex], __popcll(m));
        }
    }
    __syncthreads();
    if (tid == 0) {
        int s = 0;
        for (int e = 0; e < NEXP; ++e) { off[e] = s; base[e] = s; s += cnt[e]; }
        off[NEXP] = s;
        int t = 0;
        for (int e = 0; e < NEXP; ++e)
            for (int m0 = off[e]; m0 < off[e + 1]; m0 += 128)
                table[t++] = (e << 13) | m0;
        for (; t < TSLOTS; ++t) table[t] = -1;
    }
    __syncthreads();
    for (int i = tid; i < TOKENS; i += 1024) {
        int e = idx[i];
#pragma unroll
        for (int ex = 0; ex < NEXP; ++ex) {
            unsigned long long m = __ballot(e == ex);
            if (e == ex) {
                int lead = (int)__ffsll((long long)m) - 1;
                int pos = 0;
                if (lane == lead) pos = atomicAdd(&base[ex], __popcll(m));
                pos = __shfl(pos, lead);
                pos += __popcll(m & ((1ULL << lane) - 1ULL));
                perm[pos] = i;
            }
        }
    }
}

// ---------------- gather + convert x into sorted bf16 rows ------------------
__global__ void gather_x(const float* __restrict__ x, const int* __restrict__ perm,
                         unsigned short* __restrict__ xg) {
    const int row = blockIdx.x, t = threadIdx.x;
    const int src = perm[row];
    float4 v = *(const float4*)(x + (size_t)src * IN_F + t * 4);
    unsigned long long pk =
        (unsigned long long)f2bf(v.x) |
        ((unsigned long long)f2bf(v.y) << 16) |
        ((unsigned long long)f2bf(v.z) << 32) |
        ((unsigned long long)f2bf(v.w) << 48);
    *(unsigned long long*)(xg + (size_t)row * IN_F + t * 4) = pk;
}

// ---------------- transpose + convert: fp32 [E][R][C] -> bf16 [E][C][R] -----
__global__ void transp(const float* __restrict__ in, unsigned short* __restrict__ out,
                       int R, int C) {
    __shared__ unsigned short T[64 * 65];
    const int e = blockIdx.z;
    const int r0 = blockIdx.y * 64, c0 = blockIdx.x * 64;
    const int tid = threadIdx.x;
    const int rr = tid >> 4, cc = tid & 15;
    const float* ip = in + ((size_t)e * R + r0) * C + c0;
#pragma unroll
    for (int p = 0; p < 4; ++p) {
        int r = p * 16 + rr;
        float4 v = *(const float4*)(ip + (size_t)r * C + cc * 4);
        T[(cc * 4 + 0) * 65 + r] = f2bf(v.x);
        T[(cc * 4 + 1) * 65 + r] = f2bf(v.y);
        T[(cc * 4 + 2) * 65 + r] = f2bf(v.z);
        T[(cc * 4 + 3) * 65 + r] = f2bf(v.w);
    }
    __syncthreads();
    unsigned short* op = out + ((size_t)e * C + c0) * R + r0;
    const int c = tid >> 2, ch = tid & 3;
    u16x8 a, b;
#pragma unroll
    for (int i = 0; i < 8; ++i) a[i] = T[c * 65 + ch * 16 + i];
#pragma unroll
    for (int i = 0; i < 8; ++i) b[i] = T[c * 65 + ch * 16 + 8 + i];
    *(u16x8*)(op + (size_t)c * R + ch * 16) = a;
    *(u16x8*)(op + (size_t)c * R + ch * 16 + 8) = b;
}

// ---------------- grouped GEMM, counted-vmcnt 4-slot ring pipeline ----------
// K-slab = 32. LDS ring: 4 slots x (A[128x32] + B[128x32]) bf16 = 64 KB.
// Per slab s: vmcnt(8) -> s_barrier -> stage(s+3) into slot (s-1)&3 ->
// ds_read slot s&3 -> setprio(1) 16 MFMA setprio(0). vmcnt never 0 mid-loop.
template<int K, int ND, bool GELU>
__launch_bounds__(256, 2)
__global__ void moe_gemm_pipe(const unsigned short* __restrict__ A,
                              const unsigned short* __restrict__ W,
                              const float* __restrict__ bias,
                              const int* __restrict__ perm,
                              const int* __restrict__ off,
                              const int* __restrict__ table,
                              void* __restrict__ outp) {
    const int nwg = (ND / 128) * TSLOTS;
    const int chunk = nwg >> 3;
    const int bid = blockIdx.x;
    const int logical = (bid & 7) * chunk + (bid >> 3);
    const int nt = logical / TSLOTS;
    const int t  = logical - nt * TSLOTS;
    const int te = table[t];
    if (te < 0) return;
    const int e  = te >> 13;
    const int m0 = te & 8191;
    const int sege = off[e + 1];
    const int n0 = nt * 128;

    __shared__ __align__(16) unsigned char L[65536];   // 4 slots x 16 KB

    const int tid = threadIdx.x;
    const int wid = tid >> 6, lane = tid & 63;
    const int wm = (wid >> 1) * 64, wn = (wid & 1) * 64;
    const int lr = lane & 15, hk = lane >> 4;

    const unsigned short* We = W + (size_t)e * ND * K + (size_t)n0 * K;

    // Staging: slab = 128 rows x 32 k x 2B per operand = 512 chunks of 16B.
    // Thread covers chunk ids {tid, tid+256}; row = id>>2, slot-chunk = id&3.
    // Source chunk pre-swizzled: g = c ^ ((row>>1)&3)  (involution).
    const int id0 = tid, id1 = tid + 256;
    const int ar0 = id0 >> 2, ac0 = (id0 & 3) ^ ((ar0 >> 1) & 3);
    const int ar1 = id1 >> 2, ac1 = (id1 & 3) ^ ((ar1 >> 1) & 3);
    int ga0 = m0 + ar0; if (ga0 > TOKENS - 1) ga0 = TOKENS - 1;
    int ga1 = m0 + ar1; if (ga1 > TOKENS - 1) ga1 = TOKENS - 1;
    const unsigned short* sA0 = A + (size_t)ga0 * K + ac0 * 8;
    const unsigned short* sA1 = A + (size_t)ga1 * K + ac1 * 8;
    const unsigned short* sB0 = We + (size_t)ar0 * K + ac0 * 8;
    const unsigned short* sB1 = We + (size_t)ar1 * K + ac1 * 8;
    const int du = wid * 1024;   // wave-uniform LDS dest (HW adds lane*16)

    constexpr int NS = K / 32;

    auto stage = [&](int s) {
        unsigned char* base = L + (s & 3) * 16384;
        const int ko = s * 32;
        gload_lds16(sA0 + ko, base + du);
        gload_lds16(sA1 + ko, base + 4096 + du);
        gload_lds16(sB0 + ko, base + 8192 + du);
        gload_lds16(sB1 + ko, base + 12288 + du);
    };

    f32x4 acc[4][4];
#pragma unroll
    for (int i = 0; i < 4; ++i)
#pragma unroll
        for (int j = 0; j < 4; ++j) acc[i][j] = (f32x4){0.f, 0.f, 0.f, 0.f};

    stage(0); stage(1); stage(2);

    for (int s = 0; s < NS; ++s) {
        const int rem = NS - 1 - s;
        if (rem >= 2)      asm volatile("s_waitcnt vmcnt(8)" ::: "memory");
        else if (rem == 1) asm volatile("s_waitcnt vmcnt(4)" ::: "memory");
        else               asm volatile("s_waitcnt vmcnt(0)" ::: "memory");
        __builtin_amdgcn_s_barrier();
        __builtin_amdgcn_sched_barrier(0);
        if (s + 3 < NS) stage(s + 3);

        const unsigned char* base = L + (s & 3) * 16384;
        bf16x8 a[4], b[4];
#pragma unroll
        for (int m = 0; m < 4; ++m) {
            int row = wm + m * 16 + lr;
            a[m] = *(const bf16x8*)(base + row * 64 + ((hk ^ ((row >> 1) & 3)) << 4));
        }
#pragma unroll
        for (int n = 0; n < 4; ++n) {
            int row = wn + n * 16 + lr;
            b[n] = *(const bf16x8*)(base + 8192 + row * 64 + ((hk ^ ((row >> 1) & 3)) << 4));
        }
        __builtin_amdgcn_s_setprio(1);
#pragma unroll
        for (int m = 0; m < 4; ++m)
#pragma unroll
            for (int n = 0; n < 4; ++n)
                acc[m][n] = __builtin_amdgcn_mfma_f32_16x16x32_bf16(a[m], b[n], acc[m][n], 0, 0, 0);
        __builtin_amdgcn_s_setprio(0);
    }

    const float* be = bias + (size_t)e * ND + n0;
#pragma unroll
    for (int m = 0; m < 4; ++m) {
#pragma unroll
        for (int r = 0; r < 4; ++r) {
            int row = wm + m * 16 + hk * 4 + r;
            int grow = m0 + row;
            if (grow >= sege) continue;
            if constexpr (GELU) {
                unsigned short* h = (unsigned short*)outp;
                size_t base = (size_t)grow * ND + n0;
#pragma unroll
                for (int n = 0; n < 4; ++n) {
                    int col = wn + n * 16 + lr;
                    float v = acc[m][n][r] + be[col];
                    float u = v * (0.7978845608f + 0.0356774081f * v * v);
                    float g = v / (1.0f + __expf(-2.0f * u));
                    h[base + col] = f2bf(g);
                }
            } else {
                float* out = (float*)outp;
                int tok = perm[grow];
                size_t base = (size_t)tok * ND + n0;
#pragma unroll
                for (int n = 0; n < 4; ++n) {
                    int col = wn + n * 16 + lr;
                    out[base + col] = acc[m][n][r] + be[col];
                }
            }
        }
    }
}

extern "C" void kernel_launch(void* const* d_in, const int* in_sizes, int n_in,
                              void* d_out, int out_size, void* d_ws, size_t ws_size,
                              hipStream_t stream) {
    const float* x   = (const float*)d_in[0];
    const int*   idx = (const int*)d_in[1];
    const float* w1  = (const float*)d_in[2];
    const float* w2  = (const float*)d_in[3];
    const float* b1  = (const float*)d_in[4];
    const float* b2  = (const float*)d_in[5];
    float* out = (float*)d_out;

    int* perm  = (int*)d_ws;
    int* off   = perm + TOKENS;
    int* table = off + 16;
    unsigned short* xg = (unsigned short*)((char*)d_ws + 65536);
    unsigned short* h  = xg + (size_t)TOKENS * IN_F;
    unsigned short* wt = h + (size_t)TOKENS * HID_F;   // shared W1t/W2t buffer (64MB)

    hipLaunchKernelGGL(sort_kernel, dim3(1), dim3(1024), 0, stream, idx, perm, off, table);
    hipLaunchKernelGGL(gather_x, dim3(TOKENS), dim3(256), 0, stream, x, perm, xg);

    // W1 [E][1024][4096] -> wt [E][4096][1024]
    hipLaunchKernelGGL(transp, dim3(HID_F / 64, IN_F / 64, NEXP), dim3(256), 0, stream,
                       w1, wt, IN_F, HID_F);
    hipLaunchKernelGGL((moe_gemm_pipe<IN_F, HID_F, true>), dim3((HID_F / 128) * TSLOTS), dim3(256),
                       0, stream, xg, wt, b1, perm, off, table, (void*)h);

    // W2 [E][4096][1024] -> wt [E][1024][4096]
    hipLaunchKernelGGL(transp, dim3(OUT_F / 64, HID_F / 64, NEXP), dim3(256), 0, stream,
                       w2, wt, HID_F, OUT_F);
    hipLaunchKernelGGL((moe_gemm_pipe<HID_F, OUT_F, false>), dim3((OUT_F / 128) * TSLOTS), dim3(256),
                       0, stream, h, wt, b2, perm, off, table, (void*)out);
}

// Round 5
// 354.853 us; speedup vs baseline: 1.0358x; 1.0358x over previous
//
#include <hip/hip_runtime.h>
#include <hip/hip_bf16.h>
#include <math.h>

#define TOKENS 8192
#define IN_F   1024
#define HID_F  4096
#define OUT_F  1024
#define NEXP   8
#define TSLOTS 72   // max total M-tiles: TOKENS/128 + NEXP partials

typedef __attribute__((ext_vector_type(8))) short bf16x8;
typedef __attribute__((ext_vector_type(4))) float f32x4;
typedef __attribute__((ext_vector_type(8))) unsigned short u16x8;

__device__ __forceinline__ unsigned short f2bf(float f) {
    unsigned int u = __float_as_uint(f);
    u += 0x7fffu + ((u >> 16) & 1u);   // round-to-nearest-even
    return (unsigned short)(u >> 16);
}

__device__ __forceinline__ void gload_lds16(const unsigned short* g, unsigned char* lds) {
    __builtin_amdgcn_global_load_lds(
        (const __attribute__((address_space(1))) void*)g,
        (__attribute__((address_space(3))) void*)lds, 16, 0, 0);
}

// ---------------- sort + tile-table build -----------------------------------
__global__ void sort_kernel(const int* __restrict__ idx, int* __restrict__ perm,
                            int* __restrict__ off, int* __restrict__ table) {
    __shared__ int cnt[NEXP];
    __shared__ int base[NEXP];
    const int tid = threadIdx.x, lane = tid & 63;
    if (tid < NEXP) cnt[tid] = 0;
    __syncthreads();
    for (int i = tid; i < TOKENS; i += 1024) {
        int e = idx[i];
#pragma unroll
        for (int ex = 0; ex < NEXP; ++ex) {
            unsigned long long m = __ballot(e == ex);
            if (lane == 0 && m) atomicAdd(&cnt[ex], __popcll(m));
        }
    }
    __syncthreads();
    if (tid == 0) {
        int s = 0;
        for (int e = 0; e < NEXP; ++e) { off[e] = s; base[e] = s; s += cnt[e]; }
        off[NEXP] = s;
        int t = 0;
        for (int e = 0; e < NEXP; ++e)
            for (int m0 = off[e]; m0 < off[e + 1]; m0 += 128)
                table[t++] = (e << 13) | m0;
        for (; t < TSLOTS; ++t) table[t] = -1;
    }
    __syncthreads();
    for (int i = tid; i < TOKENS; i += 1024) {
        int e = idx[i];
#pragma unroll
        for (int ex = 0; ex < NEXP; ++ex) {
            unsigned long long m = __ballot(e == ex);
            if (e == ex) {
                int lead = (int)__ffsll((long long)m) - 1;
                int pos = 0;
                if (lane == lead) pos = atomicAdd(&base[ex], __popcll(m));
                pos = __shfl(pos, lead);
                pos += __popcll(m & ((1ULL << lane) - 1ULL));
                perm[pos] = i;
            }
        }
    }
}

// ---------------- gather + convert x into sorted bf16 rows ------------------
__global__ void gather_x(const float* __restrict__ x, const int* __restrict__ perm,
                         unsigned short* __restrict__ xg) {
    const int row = blockIdx.x, t = threadIdx.x;
    const int src = perm[row];
    float4 v = *(const float4*)(x + (size_t)src * IN_F + t * 4);
    unsigned long long pk =
        (unsigned long long)f2bf(v.x) |
        ((unsigned long long)f2bf(v.y) << 16) |
        ((unsigned long long)f2bf(v.z) << 32) |
        ((unsigned long long)f2bf(v.w) << 48);
    *(unsigned long long*)(xg + (size_t)row * IN_F + t * 4) = pk;
}

// ---------------- transpose + convert: fp32 [E][R][C] -> bf16 [E][C][R] -----
__global__ void transp(const float* __restrict__ in, unsigned short* __restrict__ out,
                       int R, int C) {
    __shared__ unsigned short T[64 * 65];
    const int e = blockIdx.z;
    const int r0 = blockIdx.y * 64, c0 = blockIdx.x * 64;
    const int tid = threadIdx.x;
    const int rr = tid >> 4, cc = tid & 15;
    const float* ip = in + ((size_t)e * R + r0) * C + c0;
#pragma unroll
    for (int p = 0; p < 4; ++p) {
        int r = p * 16 + rr;
        float4 v = *(const float4*)(ip + (size_t)r * C + cc * 4);
        T[(cc * 4 + 0) * 65 + r] = f2bf(v.x);
        T[(cc * 4 + 1) * 65 + r] = f2bf(v.y);
        T[(cc * 4 + 2) * 65 + r] = f2bf(v.z);
        T[(cc * 4 + 3) * 65 + r] = f2bf(v.w);
    }
    __syncthreads();
    unsigned short* op = out + ((size_t)e * C + c0) * R + r0;
    const int c = tid >> 2, ch = tid & 3;
    u16x8 a, b;
#pragma unroll
    for (int i = 0; i < 8; ++i) a[i] = T[c * 65 + ch * 16 + i];
#pragma unroll
    for (int i = 0; i < 8; ++i) b[i] = T[c * 65 + ch * 16 + 8 + i];
    *(u16x8*)(op + (size_t)c * R + ch * 16) = a;
    *(u16x8*)(op + (size_t)c * R + ch * 16 + 8) = b;
}

// ---------------- grouped GEMM, counted-vmcnt 3-slot ring pipeline ----------
// K-slab = 32. LDS ring: 3 slots x (A[128x32] + B[128x32]) bf16 = 48 KB
// -> 3 blocks/CU (TLP preserved, unlike the 64 KB 4-ring which dropped to
// ~1 block/CU and regressed). Per slab s: vmcnt(4) (slab s landed, s+1 in
// flight) -> s_barrier -> stage(s+2) into the slot freed at s-1 ->
// ds_read slot s -> setprio(1) 16 MFMA setprio(0). vmcnt never 0 mid-loop.
template<int K, int ND, bool GELU>
__launch_bounds__(256, 3)
__global__ void moe_gemm_pipe(const unsigned short* __restrict__ A,
                              const unsigned short* __restrict__ W,
                              const float* __restrict__ bias,
                              const int* __restrict__ perm,
                              const int* __restrict__ off,
                              const int* __restrict__ table,
                              void* __restrict__ outp) {
    const int nwg = (ND / 128) * TSLOTS;
    const int chunk = nwg >> 3;
    const int bid = blockIdx.x;
    const int logical = (bid & 7) * chunk + (bid >> 3);
    const int nt = logical / TSLOTS;
    const int t  = logical - nt * TSLOTS;
    const int te = table[t];
    if (te < 0) return;
    const int e  = te >> 13;
    const int m0 = te & 8191;
    const int sege = off[e + 1];
    const int n0 = nt * 128;

    __shared__ __align__(16) unsigned char L[49152];   // 3 slots x 16 KB

    const int tid = threadIdx.x;
    const int wid = tid >> 6, lane = tid & 63;
    const int wm = (wid >> 1) * 64, wn = (wid & 1) * 64;
    const int lr = lane & 15, hk = lane >> 4;

    const unsigned short* We = W + (size_t)e * ND * K + (size_t)n0 * K;

    // Staging: slab = 128 rows x 32 k x 2B per operand = 512 chunks of 16B.
    // Thread covers chunk ids {tid, tid+256}; row = id>>2, slot-chunk = id&3.
    // Source chunk pre-swizzled: g = c ^ ((row>>1)&3)  (involution).
    const int id0 = tid, id1 = tid + 256;
    const int ar0 = id0 >> 2, ac0 = (id0 & 3) ^ ((ar0 >> 1) & 3);
    const int ar1 = id1 >> 2, ac1 = (id1 & 3) ^ ((ar1 >> 1) & 3);
    int ga0 = m0 + ar0; if (ga0 > TOKENS - 1) ga0 = TOKENS - 1;
    int ga1 = m0 + ar1; if (ga1 > TOKENS - 1) ga1 = TOKENS - 1;
    const unsigned short* sA0 = A + (size_t)ga0 * K + ac0 * 8;
    const unsigned short* sA1 = A + (size_t)ga1 * K + ac1 * 8;
    const unsigned short* sB0 = We + (size_t)ar0 * K + ac0 * 8;
    const unsigned short* sB1 = We + (size_t)ar1 * K + ac1 * 8;
    const int du = wid * 1024;   // wave-uniform LDS dest (HW adds lane*16)

    constexpr int NS = K / 32;

    auto stage = [&](int s, int slot) {
        unsigned char* base = L + slot * 16384;
        const int ko = s * 32;
        gload_lds16(sA0 + ko, base + du);
        gload_lds16(sA1 + ko, base + 4096 + du);
        gload_lds16(sB0 + ko, base + 8192 + du);
        gload_lds16(sB1 + ko, base + 12288 + du);
    };

    f32x4 acc[4][4];
#pragma unroll
    for (int i = 0; i < 4; ++i)
#pragma unroll
        for (int j = 0; j < 4; ++j) acc[i][j] = (f32x4){0.f, 0.f, 0.f, 0.f};

    stage(0, 0); stage(1, 1);

    int slot_r = 0;   // slot holding slab s
    int slot_w = 2;   // slot for slab s+2
    for (int s = 0; s < NS; ++s) {
        if (s < NS - 1) asm volatile("s_waitcnt vmcnt(4)" ::: "memory");
        else            asm volatile("s_waitcnt vmcnt(0)" ::: "memory");
        __builtin_amdgcn_s_barrier();
        __builtin_amdgcn_sched_barrier(0);
        if (s + 2 < NS) stage(s + 2, slot_w);

        const unsigned char* base = L + slot_r * 16384;
        bf16x8 a[4], b[4];
#pragma unroll
        for (int m = 0; m < 4; ++m) {
            int row = wm + m * 16 + lr;
            a[m] = *(const bf16x8*)(base + row * 64 + ((hk ^ ((row >> 1) & 3)) << 4));
        }
#pragma unroll
        for (int n = 0; n < 4; ++n) {
            int row = wn + n * 16 + lr;
            b[n] = *(const bf16x8*)(base + 8192 + row * 64 + ((hk ^ ((row >> 1) & 3)) << 4));
        }
        __builtin_amdgcn_s_setprio(1);
#pragma unroll
        for (int m = 0; m < 4; ++m)
#pragma unroll
            for (int n = 0; n < 4; ++n)
                acc[m][n] = __builtin_amdgcn_mfma_f32_16x16x32_bf16(a[m], b[n], acc[m][n], 0, 0, 0);
        __builtin_amdgcn_s_setprio(0);

        slot_r = (slot_r == 2) ? 0 : slot_r + 1;
        slot_w = (slot_w == 2) ? 0 : slot_w + 1;
    }

    const float* be = bias + (size_t)e * ND + n0;
#pragma unroll
    for (int m = 0; m < 4; ++m) {
#pragma unroll
        for (int r = 0; r < 4; ++r) {
            int row = wm + m * 16 + hk * 4 + r;
            int grow = m0 + row;
            if (grow >= sege) continue;
            if constexpr (GELU) {
                unsigned short* h = (unsigned short*)outp;
                size_t base = (size_t)grow * ND + n0;
#pragma unroll
                for (int n = 0; n < 4; ++n) {
                    int col = wn + n * 16 + lr;
                    float v = acc[m][n][r] + be[col];
                    float u = v * (0.7978845608f + 0.0356774081f * v * v);
                    float g = v / (1.0f + __expf(-2.0f * u));
                    h[base + col] = f2bf(g);
                }
            } else {
                float* out = (float*)outp;
                int tok = perm[grow];
                size_t base = (size_t)tok * ND + n0;
#pragma unroll
                for (int n = 0; n < 4; ++n) {
                    int col = wn + n * 16 + lr;
                    out[base + col] = acc[m][n][r] + be[col];
                }
            }
        }
    }
}

extern "C" void kernel_launch(void* const* d_in, const int* in_sizes, int n_in,
                              void* d_out, int out_size, void* d_ws, size_t ws_size,
                              hipStream_t stream) {
    const float* x   = (const float*)d_in[0];
    const int*   idx = (const int*)d_in[1];
    const float* w1  = (const float*)d_in[2];
    const float* w2  = (const float*)d_in[3];
    const float* b1  = (const float*)d_in[4];
    const float* b2  = (const float*)d_in[5];
    float* out = (float*)d_out;

    int* perm  = (int*)d_ws;
    int* off   = perm + TOKENS;
    int* table = off + 16;
    unsigned short* xg = (unsigned short*)((char*)d_ws + 65536);
    unsigned short* h  = xg + (size_t)TOKENS * IN_F;
    unsigned short* wt = h + (size_t)TOKENS * HID_F;   // shared W1t/W2t buffer (64MB)

    hipLaunchKernelGGL(sort_kernel, dim3(1), dim3(1024), 0, stream, idx, perm, off, table);
    hipLaunchKernelGGL(gather_x, dim3(TOKENS), dim3(256), 0, stream, x, perm, xg);

    // W1 [E][1024][4096] -> wt [E][4096][1024]
    hipLaunchKernelGGL(transp, dim3(HID_F / 64, IN_F / 64, NEXP), dim3(256), 0, stream,
                       w1, wt, IN_F, HID_F);
    hipLaunchKernelGGL((moe_gemm_pipe<IN_F, HID_F, true>), dim3((HID_F / 128) * TSLOTS), dim3(256),
                       0, stream, xg, wt, b1, perm, off, table, (void*)h);

    // W2 [E][4096][1024] -> wt [E][1024][4096]
    hipLaunchKernelGGL(transp, dim3(OUT_F / 64, HID_F / 64, NEXP), dim3(256), 0, stream,
                       w2, wt, HID_F, OUT_F);
    hipLaunchKernelGGL((moe_gemm_pipe<HID_F, OUT_F, false>), dim3((OUT_F / 128) * TSLOTS), dim3(256),
                       0, stream, h, wt, b2, perm, off, table, (void*)out);
}

// Round 6
// 341.745 us; speedup vs baseline: 1.0755x; 1.0384x over previous
//
#include <hip/hip_runtime.h>
#include <hip/hip_bf16.h>
#include <math.h>

#define TOKENS 8192
#define IN_F   1024
#define HID_F  4096
#define OUT_F  1024
#define NEXP   8
#define TSLOTS 40   // max total 256-row M-tiles: TOKENS/256 + NEXP partials

typedef __attribute__((ext_vector_type(8))) short bf16x8;
typedef __attribute__((ext_vector_type(4))) float f32x4;
typedef __attribute__((ext_vector_type(8))) unsigned short u16x8;

__device__ __forceinline__ unsigned short f2bf(float f) {
    unsigned int u = __float_as_uint(f);
    u += 0x7fffu + ((u >> 16) & 1u);   // round-to-nearest-even
    return (unsigned short)(u >> 16);
}

__device__ __forceinline__ void gload_lds16(const unsigned short* g, unsigned char* lds) {
    __builtin_amdgcn_global_load_lds(
        (const __attribute__((address_space(1))) void*)g,
        (__attribute__((address_space(3))) void*)lds, 16, 0, 0);
}

// ---------------- sort + tile-table build (256-row tiles) -------------------
__global__ void sort_kernel(const int* __restrict__ idx, int* __restrict__ perm,
                            int* __restrict__ off, int* __restrict__ table) {
    __shared__ int cnt[NEXP];
    __shared__ int base[NEXP];
    const int tid = threadIdx.x, lane = tid & 63;
    if (tid < NEXP) cnt[tid] = 0;
    __syncthreads();
    for (int i = tid; i < TOKENS; i += 1024) {
        int e = idx[i];
#pragma unroll
        for (int ex = 0; ex < NEXP; ++ex) {
            unsigned long long m = __ballot(e == ex);
            if (lane == 0 && m) atomicAdd(&cnt[ex], __popcll(m));
        }
    }
    __syncthreads();
    if (tid == 0) {
        int s = 0;
        for (int e = 0; e < NEXP; ++e) { off[e] = s; base[e] = s; s += cnt[e]; }
        off[NEXP] = s;
        int t = 0;
        for (int e = 0; e < NEXP; ++e)
            for (int m0 = off[e]; m0 < off[e + 1]; m0 += 256)
                table[t++] = (e << 13) | m0;
        for (; t < TSLOTS; ++t) table[t] = -1;
    }
    __syncthreads();
    for (int i = tid; i < TOKENS; i += 1024) {
        int e = idx[i];
#pragma unroll
        for (int ex = 0; ex < NEXP; ++ex) {
            unsigned long long m = __ballot(e == ex);
            if (e == ex) {
                int lead = (int)__ffsll((long long)m) - 1;
                int pos = 0;
                if (lane == lead) pos = atomicAdd(&base[ex], __popcll(m));
                pos = __shfl(pos, lead);
                pos += __popcll(m & ((1ULL << lane) - 1ULL));
                perm[pos] = i;
            }
        }
    }
}

// ---------------- gather + convert x into sorted bf16 rows ------------------
__global__ void gather_x(const float* __restrict__ x, const int* __restrict__ perm,
                         unsigned short* __restrict__ xg) {
    const int row = blockIdx.x, t = threadIdx.x;
    const int src = perm[row];
    float4 v = *(const float4*)(x + (size_t)src * IN_F + t * 4);
    unsigned long long pk =
        (unsigned long long)f2bf(v.x) |
        ((unsigned long long)f2bf(v.y) << 16) |
        ((unsigned long long)f2bf(v.z) << 32) |
        ((unsigned long long)f2bf(v.w) << 48);
    *(unsigned long long*)(xg + (size_t)row * IN_F + t * 4) = pk;
}

// ---------------- transpose + convert: fp32 [E][R][C] -> bf16 [E][C][R] -----
__global__ void transp(const float* __restrict__ in, unsigned short* __restrict__ out,
                       int R, int C) {
    __shared__ unsigned short T[64 * 65];
    const int e = blockIdx.z;
    const int r0 = blockIdx.y * 64, c0 = blockIdx.x * 64;
    const int tid = threadIdx.x;
    const int rr = tid >> 4, cc = tid & 15;
    const float* ip = in + ((size_t)e * R + r0) * C + c0;
#pragma unroll
    for (int p = 0; p < 4; ++p) {
        int r = p * 16 + rr;
        float4 v = *(const float4*)(ip + (size_t)r * C + cc * 4);
        T[(cc * 4 + 0) * 65 + r] = f2bf(v.x);
        T[(cc * 4 + 1) * 65 + r] = f2bf(v.y);
        T[(cc * 4 + 2) * 65 + r] = f2bf(v.z);
        T[(cc * 4 + 3) * 65 + r] = f2bf(v.w);
    }
    __syncthreads();
    unsigned short* op = out + ((size_t)e * C + c0) * R + r0;
    const int c = tid >> 2, ch = tid & 3;
    u16x8 a, b;
#pragma unroll
    for (int i = 0; i < 8; ++i) a[i] = T[c * 65 + ch * 16 + i];
#pragma unroll
    for (int i = 0; i < 8; ++i) b[i] = T[c * 65 + ch * 16 + 8 + i];
    *(u16x8*)(op + (size_t)c * R + ch * 16) = a;
    *(u16x8*)(op + (size_t)c * R + ch * 16 + 8) = b;
}

// ---------------- grouped GEMM: 256x256 tile, BK=64, 8 waves, counted vmcnt -
// LDS 128 KB: 2 buffers x (A[256][64] + B[256][64]) bf16. One block/CU.
// Per K-tile t: barrier; stage A-half0(t+1); vmcnt(2); barrier; then
// {ds_read fragments interleaved with staging A1/B0/B1 of t+1} + 64 MFMA.
// vmcnt never drains to 0 mid-loop (T4); stages always target buf[(t+1)&1]
// which no wave reads during tile t (race-free by the two barriers).
template<int K, int ND, bool GELU>
__launch_bounds__(512, 2)
__global__ void moe_gemm256(const unsigned short* __restrict__ A,
                            const unsigned short* __restrict__ W,
                            const float* __restrict__ bias,
                            const int* __restrict__ perm,
                            const int* __restrict__ off,
                            const int* __restrict__ table,
                            void* __restrict__ outp) {
    const int nwg = (ND / 256) * TSLOTS;
    const int chunk = nwg >> 3;
    const int logical = ((int)blockIdx.x & 7) * chunk + ((int)blockIdx.x >> 3);
    const int nt = logical / TSLOTS;
    const int t0 = logical - nt * TSLOTS;
    const int te = table[t0];
    if (te < 0) return;
    const int e  = te >> 13;
    const int m0 = te & 8191;
    const int sege = off[e + 1];
    const int n0 = nt * 256;

    __shared__ __align__(16) unsigned char L[131072];  // [buf][op][256 rows][128B]

    const int tid = threadIdx.x;
    const int wid = tid >> 6, lane = tid & 63;
    const int wr = wid >> 2, wc = wid & 3;             // 2M x 4N wave grid
    const int lr = lane & 15, hk = lane >> 4;

    const unsigned short* We = W + (size_t)e * ND * K + (size_t)n0 * K;

    // Staging: call cc (0..3) covers rows cc*64 + wid*8 + (lane>>3), 8 chunks of
    // 16B per 8-row group. LDS[row][w] = global chunk w ^ (row&7) (involution).
    const int srow8 = lane >> 3;
    const int sch   = (lane & 7) ^ srow8;
    // per-thread source pointers (k-tile offset added per stage)
    const unsigned short* aSrc[4];
    const unsigned short* wSrc[4];
#pragma unroll
    for (int cc = 0; cc < 4; ++cc) {
        int rt = cc * 64 + wid * 8 + srow8;
        int ga = m0 + rt; if (ga > TOKENS - 1) ga = TOKENS - 1;
        aSrc[cc] = A  + (size_t)ga * K + sch * 8;
        wSrc[cc] = We + (size_t)rt * K + sch * 8;
    }
    const int dstBase = wid * 1024;                    // + cc*8192 + op*32768 + buf*65536

    constexpr int NT = K / 64;

    // h: 0=A-half0, 1=A-half1, 2=B-half0, 3=B-half1 (2 gload_lds each)
    auto stageH = [&](int tile, int h) {
        const int buf = (tile & 1) * 65536;
        const int op  = (h >> 1) * 32768;
        const int c0_ = (h & 1) * 2;
        const int ko  = tile * 64;
#pragma unroll
        for (int j = 0; j < 2; ++j) {
            int cc = c0_ + j;
            const unsigned short* s = (h < 2) ? (aSrc[cc] + ko) : (wSrc[cc] + ko);
            gload_lds16(s, L + buf + op + cc * 8192 + dstBase);
        }
    };

    f32x4 acc[8][4];
#pragma unroll
    for (int i = 0; i < 8; ++i)
#pragma unroll
        for (int j = 0; j < 4; ++j) acc[i][j] = (f32x4){0.f, 0.f, 0.f, 0.f};

    // prologue: tile 0 fully staged (8 loads in flight)
#pragma unroll
    for (int h = 0; h < 4; ++h) stageH(0, h);

    const int xorc = (lr & 7) << 4;

    for (int t = 0; t < NT; ++t) {
        __builtin_amdgcn_s_barrier();                  // all reads of buf[(t+1)&1] done
        if (t + 1 < NT) {
            stageH(t + 1, 0);
            asm volatile("s_waitcnt vmcnt(2)" ::: "memory");  // tile t landed
        } else {
            asm volatile("s_waitcnt vmcnt(0)" ::: "memory");
        }
        __builtin_amdgcn_s_barrier();                  // landing visible to all waves
        __builtin_amdgcn_sched_barrier(0);

        const unsigned char* rb = L + (t & 1) * 65536;

        bf16x8 b[4][2];
#pragma unroll
        for (int n = 0; n < 4; ++n) {
            int row = wc * 64 + n * 16 + lr;
#pragma unroll
            for (int kk = 0; kk < 2; ++kk)
                b[n][kk] = *(const bf16x8*)(rb + 32768 + row * 128 + ((((kk * 4 + hk) << 4) ^ xorc)));
        }

        bf16x8 a[4][2];
#pragma unroll
        for (int m = 0; m < 4; ++m) {
            int row = wr * 128 + m * 16 + lr;
#pragma unroll
            for (int kk = 0; kk < 2; ++kk)
                a[m][kk] = *(const bf16x8*)(rb + row * 128 + ((((kk * 4 + hk) << 4) ^ xorc)));
        }
        if (t + 1 < NT) stageH(t + 1, 1);
        __builtin_amdgcn_s_setprio(1);
#pragma unroll
        for (int m = 0; m < 4; ++m)
#pragma unroll
            for (int n = 0; n < 4; ++n)
#pragma unroll
                for (int kk = 0; kk < 2; ++kk)
                    acc[m][n] = __builtin_amdgcn_mfma_f32_16x16x32_bf16(a[m][kk], b[n][kk], acc[m][n], 0, 0, 0);
        __builtin_amdgcn_s_setprio(0);

#pragma unroll
        for (int m = 0; m < 4; ++m) {
            int row = wr * 128 + 64 + m * 16 + lr;
#pragma unroll
            for (int kk = 0; kk < 2; ++kk)
                a[m][kk] = *(const bf16x8*)(rb + row * 128 + ((((kk * 4 + hk) << 4) ^ xorc)));
        }
        if (t + 1 < NT) stageH(t + 1, 2);
        __builtin_amdgcn_s_setprio(1);
#pragma unroll
        for (int m = 0; m < 4; ++m)
#pragma unroll
            for (int n = 0; n < 4; ++n)
#pragma unroll
                for (int kk = 0; kk < 2; ++kk)
                    acc[4 + m][n] = __builtin_amdgcn_mfma_f32_16x16x32_bf16(a[m][kk], b[n][kk], acc[4 + m][n], 0, 0, 0);
        __builtin_amdgcn_s_setprio(0);
        if (t + 1 < NT) stageH(t + 1, 3);
    }

    // epilogue
    const float* be = bias + (size_t)e * ND + n0;
#pragma unroll
    for (int m = 0; m < 8; ++m) {
#pragma unroll
        for (int r = 0; r < 4; ++r) {
            int row = wr * 128 + m * 16 + hk * 4 + r;
            int grow = m0 + row;
            if (grow >= sege) continue;
            if constexpr (GELU) {
                unsigned short* h = (unsigned short*)outp;
                size_t base = (size_t)grow * ND + n0;
#pragma unroll
                for (int n = 0; n < 4; ++n) {
                    int col = wc * 64 + n * 16 + lr;
                    float v = acc[m][n][r] + be[col];
                    float u = v * (0.7978845608f + 0.0356774081f * v * v);
                    float g = v / (1.0f + __expf(-2.0f * u));
                    h[base + col] = f2bf(g);
                }
            } else {
                float* out = (float*)outp;
                int tok = perm[grow];
                size_t base = (size_t)tok * ND + n0;
#pragma unroll
                for (int n = 0; n < 4; ++n) {
                    int col = wc * 64 + n * 16 + lr;
                    out[base + col] = acc[m][n][r] + be[col];
                }
            }
        }
    }
}

extern "C" void kernel_launch(void* const* d_in, const int* in_sizes, int n_in,
                              void* d_out, int out_size, void* d_ws, size_t ws_size,
                              hipStream_t stream) {
    const float* x   = (const float*)d_in[0];
    const int*   idx = (const int*)d_in[1];
    const float* w1  = (const float*)d_in[2];
    const float* w2  = (const float*)d_in[3];
    const float* b1  = (const float*)d_in[4];
    const float* b2  = (const float*)d_in[5];
    float* out = (float*)d_out;

    int* perm  = (int*)d_ws;
    int* off   = perm + TOKENS;
    int* table = off + 16;
    unsigned short* xg = (unsigned short*)((char*)d_ws + 65536);
    unsigned short* h  = xg + (size_t)TOKENS * IN_F;
    unsigned short* wt = h + (size_t)TOKENS * HID_F;   // shared W1t/W2t buffer (64MB)

    hipLaunchKernelGGL(sort_kernel, dim3(1), dim3(1024), 0, stream, idx, perm, off, table);
    hipLaunchKernelGGL(gather_x, dim3(TOKENS), dim3(256), 0, stream, x, perm, xg);

    // W1 [E][1024][4096] -> wt [E][4096][1024]
    hipLaunchKernelGGL(transp, dim3(HID_F / 64, IN_F / 64, NEXP), dim3(256), 0, stream,
                       w1, wt, IN_F, HID_F);
    hipLaunchKernelGGL((moe_gemm256<IN_F, HID_F, true>), dim3((HID_F / 256) * TSLOTS), dim3(512),
                       0, stream, xg, wt, b1, perm, off, table, (void*)h);

    // W2 [E][4096][1024] -> wt [E][1024][4096]
    hipLaunchKernelGGL(transp, dim3(OUT_F / 64, HID_F / 64, NEXP), dim3(256), 0, stream,
                       w2, wt, HID_F, OUT_F);
    hipLaunchKernelGGL((moe_gemm256<HID_F, OUT_F, false>), dim3((OUT_F / 256) * TSLOTS), dim3(512),
                       0, stream, h, wt, b2, perm, off, table, (void*)out);
}

// Round 8
// 337.962 us; speedup vs baseline: 1.0876x; 1.0112x over previous
//
#include <hip/hip_runtime.h>
#include <hip/hip_bf16.h>
#include <math.h>

#define TOKENS 8192
#define IN_F   1024
#define HID_F  4096
#define OUT_F  1024
#define NEXP   8
#define TSLOTS 40   // max total 256-row M-tiles: TOKENS/256 + NEXP partials

typedef __attribute__((ext_vector_type(8))) short bf16x8;
typedef __attribute__((ext_vector_type(4))) float f32x4;
typedef __attribute__((ext_vector_type(8))) unsigned short u16x8;

__device__ __forceinline__ unsigned short f2bf(float f) {
    unsigned int u = __float_as_uint(f);
    u += 0x7fffu + ((u >> 16) & 1u);   // round-to-nearest-even
    return (unsigned short)(u >> 16);
}

__device__ __forceinline__ void gload_lds16(const unsigned short* g, unsigned char* lds) {
    __builtin_amdgcn_global_load_lds(
        (const __attribute__((address_space(1))) void*)g,
        (__attribute__((address_space(3))) void*)lds, 16, 0, 0);
}

// ---------------- sort + tile-table build (256-row tiles) -------------------
__global__ void sort_kernel(const int* __restrict__ idx, int* __restrict__ perm,
                            int* __restrict__ off, int* __restrict__ table) {
    __shared__ int cnt[NEXP];
    __shared__ int base[NEXP];
    const int tid = threadIdx.x, lane = tid & 63;
    if (tid < NEXP) cnt[tid] = 0;
    __syncthreads();
    for (int i = tid; i < TOKENS; i += 1024) {
        int e = idx[i];
#pragma unroll
        for (int ex = 0; ex < NEXP; ++ex) {
            unsigned long long m = __ballot(e == ex);
            if (lane == 0 && m) atomicAdd(&cnt[ex], __popcll(m));
        }
    }
    __syncthreads();
    if (tid == 0) {
        int s = 0;
        for (int e = 0; e < NEXP; ++e) { off[e] = s; base[e] = s; s += cnt[e]; }
        off[NEXP] = s;
        int t = 0;
        for (int e = 0; e < NEXP; ++e)
            for (int m0 = off[e]; m0 < off[e + 1]; m0 += 256)
                table[t++] = (e << 13) | m0;
        for (; t < TSLOTS; ++t) table[t] = -1;
    }
    __syncthreads();
    for (int i = tid; i < TOKENS; i += 1024) {
        int e = idx[i];
#pragma unroll
        for (int ex = 0; ex < NEXP; ++ex) {
            unsigned long long m = __ballot(e == ex);
            if (e == ex) {
                int lead = (int)__ffsll((long long)m) - 1;
                int pos = 0;
                if (lane == lead) pos = atomicAdd(&base[ex], __popcll(m));
                pos = __shfl(pos, lead);
                pos += __popcll(m & ((1ULL << lane) - 1ULL));
                perm[pos] = i;
            }
        }
    }
}

// ---------------- gather + convert x into sorted bf16 rows ------------------
__global__ void gather_x(const float* __restrict__ x, const int* __restrict__ perm,
                         unsigned short* __restrict__ xg) {
    const int row = blockIdx.x, t = threadIdx.x;
    const int src = perm[row];
    float4 v = *(const float4*)(x + (size_t)src * IN_F + t * 4);
    unsigned long long pk =
        (unsigned long long)f2bf(v.x) |
        ((unsigned long long)f2bf(v.y) << 16) |
        ((unsigned long long)f2bf(v.z) << 32) |
        ((unsigned long long)f2bf(v.w) << 48);
    *(unsigned long long*)(xg + (size_t)row * IN_F + t * 4) = pk;
}

// ---------------- transpose + convert: fp32 [E][R][C] -> bf16 [E][C][R] -----
__global__ void transp(const float* __restrict__ in, unsigned short* __restrict__ out,
                       int R, int C) {
    __shared__ unsigned short T[64 * 65];
    const int e = blockIdx.z;
    const int r0 = blockIdx.y * 64, c0 = blockIdx.x * 64;
    const int tid = threadIdx.x;
    const int rr = tid >> 4, cc = tid & 15;
    const float* ip = in + ((size_t)e * R + r0) * C + c0;
#pragma unroll
    for (int p = 0; p < 4; ++p) {
        int r = p * 16 + rr;
        float4 v = *(const float4*)(ip + (size_t)r * C + cc * 4);
        T[(cc * 4 + 0) * 65 + r] = f2bf(v.x);
        T[(cc * 4 + 1) * 65 + r] = f2bf(v.y);
        T[(cc * 4 + 2) * 65 + r] = f2bf(v.z);
        T[(cc * 4 + 3) * 65 + r] = f2bf(v.w);
    }
    __syncthreads();
    unsigned short* op = out + ((size_t)e * C + c0) * R + r0;
    const int c = tid >> 2, ch = tid & 3;
    u16x8 a, b;
#pragma unroll
    for (int i = 0; i < 8; ++i) a[i] = T[c * 65 + ch * 16 + i];
#pragma unroll
    for (int i = 0; i < 8; ++i) b[i] = T[c * 65 + ch * 16 + 8 + i];
    *(u16x8*)(op + (size_t)c * R + ch * 16) = a;
    *(u16x8*)(op + (size_t)c * R + ch * 16 + 8) = b;
}

// -------- grouped GEMM: 256x256, BK=64, 8 waves, 8-phase counted-vmcnt ------
// Per phase: {ds_read quadrant frags ; stage 1 half-tile} -> s_barrier ->
// MFMA (compiler lgkm waits) -> [vmcnt at ph3/ph7, BEFORE the barrier] ->
// s_barrier. vmcnt is per-wave, so a wait must always be followed by a
// barrier before any ds_read of the newly staged buffer (R7's NaN was a
// vmcnt-after-barrier ordering bug). Stage slots: ph0:A1(T1) ph1:B0(T1)
// ph2:B1(T1) ph3:A0(T0+2) ph4:A1(T0+2) ph5:B0(T0+2) ph6:B1(T0+2) ph7:A0(T1+2).
// Waits: prologue vmcnt(2)+bar (tile0); ph3 vmcnt(2) (T1 landed, A0(T0+2)
// outstanding; last iter vmcnt(0)); ph7 vmcnt(2) (T0+2 landed, A0(T1+2)
// outstanding; skipped last iter). WAR audit: every stage target's last
// reader is >=1 read-drain barrier earlier (reads drain at their MFMA's
// lgkm wait, before the pre-MFMA barrier).
#define RD_A(RB, HALF) \
  _Pragma("unroll") for (int m_ = 0; m_ < 4; ++m_) { \
    const int row_ = wr * 128 + (HALF) * 64 + m_ * 16 + lr; \
    _Pragma("unroll") for (int kk_ = 0; kk_ < 2; ++kk_) \
      aR[m_][kk_] = *(const bf16x8*)((RB) + row_ * 128 + (((kk_ * 4 + hk) << 4) ^ xorc)); }

#define RD_B(RB, NH, DST) \
  _Pragma("unroll") for (int nn_ = 0; nn_ < 2; ++nn_) { \
    const int row_ = wc * 64 + ((NH) * 2 + nn_) * 16 + lr; \
    _Pragma("unroll") for (int kk_ = 0; kk_ < 2; ++kk_) \
      DST[nn_][kk_] = *(const bf16x8*)((RB) + 32768 + row_ * 128 + (((kk_ * 4 + hk) << 4) ^ xorc)); }

#define MFMA_Q(MH, NH, B) \
  __builtin_amdgcn_s_setprio(1); \
  _Pragma("unroll") for (int m_ = 0; m_ < 4; ++m_) \
    _Pragma("unroll") for (int nn_ = 0; nn_ < 2; ++nn_) \
      _Pragma("unroll") for (int kk_ = 0; kk_ < 2; ++kk_) \
        acc[(MH) * 4 + m_][(NH) * 2 + nn_] = __builtin_amdgcn_mfma_f32_16x16x32_bf16( \
            aR[m_][kk_], B[nn_][kk_], acc[(MH) * 4 + m_][(NH) * 2 + nn_], 0, 0, 0); \
  __builtin_amdgcn_s_setprio(0);

template<int K, int ND, bool GELU>
__launch_bounds__(512, 2)
__global__ void moe_gemm8p(const unsigned short* __restrict__ A,
                           const unsigned short* __restrict__ W,
                           const float* __restrict__ bias,
                           const int* __restrict__ perm,
                           const int* __restrict__ off,
                           const int* __restrict__ table,
                           void* __restrict__ outp) {
    const int nwg = (ND / 256) * TSLOTS;
    const int chunk = nwg >> 3;
    const int logical = ((int)blockIdx.x & 7) * chunk + ((int)blockIdx.x >> 3);
    const int nt = logical / TSLOTS;
    const int ts = logical - nt * TSLOTS;
    const int te = table[ts];
    if (te < 0) return;
    const int e  = te >> 13;
    const int m0 = te & 8191;
    const int sege = off[e + 1];
    const int n0 = nt * 256;

    __shared__ __align__(16) unsigned char L[131072];  // 2 buf x (A 32K + B 32K)

    const int tid = threadIdx.x;
    const int wid = tid >> 6, lane = tid & 63;
    const int wr = wid >> 2, wc = wid & 3;
    const int lr = lane & 15, hk = lane >> 4;

    const unsigned short* We = W + (size_t)e * ND * K + (size_t)n0 * K;

    const int srow8 = lane >> 3;
    const int sch   = (lane & 7) ^ srow8;   // pre-swizzled source chunk
    const unsigned short* aSrc[4];
    const unsigned short* wSrc[4];
#pragma unroll
    for (int cc = 0; cc < 4; ++cc) {
        int rt = cc * 64 + wid * 8 + srow8;
        int ga = m0 + rt; if (ga > TOKENS - 1) ga = TOKENS - 1;
        aSrc[cc] = A  + (size_t)ga * K + sch * 8;
        wSrc[cc] = We + (size_t)rt * K + sch * 8;
    }
    const int dstBase = wid * 1024;

    constexpr int NT = K / 64;

    // h: 0=A rows0-127, 1=A rows128-255, 2=B rows0-127, 3=B rows128-255
    auto stageH = [&](int tile, int h) {
        const int buf = (tile & 1) * 65536;
        const int op  = (h >> 1) * 32768;
        const int c0_ = (h & 1) * 2;
        const int ko  = tile * 64;
#pragma unroll
        for (int j = 0; j < 2; ++j) {
            int cc = c0_ + j;
            const unsigned short* s = (h < 2) ? (aSrc[cc] + ko) : (wSrc[cc] + ko);
            gload_lds16(s, L + buf + op + cc * 8192 + dstBase);
        }
    };

    f32x4 acc[8][4];
#pragma unroll
    for (int i = 0; i < 8; ++i)
#pragma unroll
        for (int j = 0; j < 4; ++j) acc[i][j] = (f32x4){0.f, 0.f, 0.f, 0.f};

    bf16x8 aR[4][2], b0R[2][2], b1R[2][2];
    const int xorc = (lr & 7) << 4;
    const unsigned char* rb0 = L;
    const unsigned char* rb1 = L + 65536;

    // prologue: tile0 all 4 halves (8 loads) + A0(tile1) (2 loads);
    // then wait own tile0 landed and rendezvous -> tile0 visible to all.
    stageH(0, 0); stageH(0, 1); stageH(0, 2); stageH(0, 3);
    stageH(1, 0);
    asm volatile("s_waitcnt vmcnt(2)" ::: "memory");
    __builtin_amdgcn_s_barrier();
    __builtin_amdgcn_sched_barrier(0);

#pragma unroll 1
    for (int i = 0; i < NT / 2; ++i) {
        const int T1 = 2 * i + 1;
        const bool lastIt = (i == NT / 2 - 1);
        // ---- ph0: q00 of T0 (rb0 landed: prologue / prev ph7 wait+barrier) --
        RD_A(rb0, 0); RD_B(rb0, 0, b0R);
        stageH(T1, 1);                       // A1(T1)
        __builtin_amdgcn_s_barrier();
        MFMA_Q(0, 0, b0R);
        __builtin_amdgcn_s_barrier();
        // ---- ph1: q01 ----
        RD_B(rb0, 1, b1R);
        stageH(T1, 2);                       // B0(T1)
        __builtin_amdgcn_s_barrier();
        MFMA_Q(0, 1, b1R);
        __builtin_amdgcn_s_barrier();
        // ---- ph2: q11 ----
        RD_A(rb0, 1);
        stageH(T1, 3);                       // B1(T1)
        __builtin_amdgcn_s_barrier();
        MFMA_Q(1, 1, b1R);
        __builtin_amdgcn_s_barrier();
        // ---- ph3: q10 (b-half0 re-read); then publish T1 ----
        RD_B(rb0, 0, b0R);
        if (!lastIt) stageH(T1 + 1, 0);      // A0(T0+2)
        __builtin_amdgcn_s_barrier();
        MFMA_Q(1, 0, b0R);
        if (lastIt) { asm volatile("s_waitcnt vmcnt(0)" ::: "memory"); }
        else        { asm volatile("s_waitcnt vmcnt(2)" ::: "memory"); }
        __builtin_amdgcn_s_barrier();        // T1 visible to all waves
        __builtin_amdgcn_sched_barrier(0);
        // ---- ph4: q00 of T1 ----
        RD_A(rb1, 0); RD_B(rb1, 0, b0R);
        if (!lastIt) stageH(T1 + 1, 1);      // A1(T0+2)
        __builtin_amdgcn_s_barrier();
        MFMA_Q(0, 0, b0R);
        __builtin_amdgcn_s_barrier();
        // ---- ph5: q01 ----
        RD_B(rb1, 1, b1R);
        if (!lastIt) stageH(T1 + 1, 2);      // B0(T0+2)
        __builtin_amdgcn_s_barrier();
        MFMA_Q(0, 1, b1R);
        __builtin_amdgcn_s_barrier();
        // ---- ph6: q11 ----
        RD_A(rb1, 1);
        if (!lastIt) stageH(T1 + 1, 3);      // B1(T0+2)
        __builtin_amdgcn_s_barrier();
        MFMA_Q(1, 1, b1R);
        __builtin_amdgcn_s_barrier();
        // ---- ph7: q10; then publish T0+2 ----
        RD_B(rb1, 0, b0R);
        if (!lastIt) stageH(T1 + 2, 0);      // A0(T1+2)
        __builtin_amdgcn_s_barrier();
        MFMA_Q(1, 0, b0R);
        if (!lastIt) { asm volatile("s_waitcnt vmcnt(2)" ::: "memory"); }
        __builtin_amdgcn_s_barrier();        // T0+2 visible to all waves
        __builtin_amdgcn_sched_barrier(0);
    }

    // epilogue
    const float* be = bias + (size_t)e * ND + n0;
#pragma unroll
    for (int m = 0; m < 8; ++m) {
#pragma unroll
        for (int r = 0; r < 4; ++r) {
            int row = wr * 128 + m * 16 + hk * 4 + r;
            int grow = m0 + row;
            if (grow >= sege) continue;
            if constexpr (GELU) {
                unsigned short* h = (unsigned short*)outp;
                size_t base = (size_t)grow * ND + n0;
#pragma unroll
                for (int n = 0; n < 4; ++n) {
                    int col = wc * 64 + n * 16 + lr;
                    float v = acc[m][n][r] + be[col];
                    float u = v * (0.7978845608f + 0.0356774081f * v * v);
                    float g = v / (1.0f + __expf(-2.0f * u));
                    h[base + col] = f2bf(g);
                }
            } else {
                float* out = (float*)outp;
                int tok = perm[grow];
                size_t base = (size_t)tok * ND + n0;
#pragma unroll
                for (int n = 0; n < 4; ++n) {
                    int col = wc * 64 + n * 16 + lr;
                    out[base + col] = acc[m][n][r] + be[col];
                }
            }
        }
    }
}

extern "C" void kernel_launch(void* const* d_in, const int* in_sizes, int n_in,
                              void* d_out, int out_size, void* d_ws, size_t ws_size,
                              hipStream_t stream) {
    const float* x   = (const float*)d_in[0];
    const int*   idx = (const int*)d_in[1];
    const float* w1  = (const float*)d_in[2];
    const float* w2  = (const float*)d_in[3];
    const float* b1  = (const float*)d_in[4];
    const float* b2  = (const float*)d_in[5];
    float* out = (float*)d_out;

    int* perm  = (int*)d_ws;
    int* off   = perm + TOKENS;
    int* table = off + 16;
    unsigned short* xg = (unsigned short*)((char*)d_ws + 65536);
    unsigned short* h  = xg + (size_t)TOKENS * IN_F;
    unsigned short* wt = h + (size_t)TOKENS * HID_F;   // shared W1t/W2t buffer (64MB)

    hipLaunchKernelGGL(sort_kernel, dim3(1), dim3(1024), 0, stream, idx, perm, off, table);
    hipLaunchKernelGGL(gather_x, dim3(TOKENS), dim3(256), 0, stream, x, perm, xg);

    // W1 [E][1024][4096] -> wt [E][4096][1024]
    hipLaunchKernelGGL(transp, dim3(HID_F / 64, IN_F / 64, NEXP), dim3(256), 0, stream,
                       w1, wt, IN_F, HID_F);
    hipLaunchKernelGGL((moe_gemm8p<IN_F, HID_F, true>), dim3((HID_F / 256) * TSLOTS), dim3(512),
                       0, stream, xg, wt, b1, perm, off, table, (void*)h);

    // W2 [E][4096][1024] -> wt [E][1024][4096]
    hipLaunchKernelGGL(transp, dim3(OUT_F / 64, HID_F / 64, NEXP), dim3(256), 0, stream,
                       w2, wt, HID_F, OUT_F);
    hipLaunchKernelGGL((moe_gemm8p<HID_F, OUT_F, false>), dim3((OUT_F / 256) * TSLOTS), dim3(512),
                       0, stream, h, wt, b2, perm, off, table, (void*)out);
}